// Round 5
// baseline (400.210 us; speedup 1.0000x reference)
//
#include <hip/hip_runtime.h>

// GraphSAGE (2x SAGEConv mean + global_mean_pool + linear) collapsed algebraically:
// out = (((St@W1l + Sw@W1r + Wsum*b1) @ W2l + (Sw@W1l + Sx@W1r + N*b1) @ W2r)/N + b2) @ Wout + bout
// invc_i = 1/max(indeg_i,1), ws_j = sum_{e:src=j} invc[dst_e], u_j = ws_j*invc_j,
// t_k = sum_{e:src=k} u[dst_e]; Sx/Sw/St = weighted column sums of x; Wsum = sum ws.
//
// R4: ws_size proven to be in [8.0, 14.4) MB -> C=16 is the only chunk count
// that fits (partial = C x 400 KB). Parallelism raised via NR=32 ranges
// (RSIZE=3125, 12.5 KB LDS): grid = 16x32 = 512 blocks of 1024 thr = 2
// blocks/CU on all 256 CUs (R3's C=16/NR=8 used only 64 CUs). featsums grid
// 256 -> 2048 blocks (was 6.9% occupancy, 551 GB/s).

#define NN    100000
#define NE    1600000
#define FEAT  128
#define NCLS  40
#define NR    32
#define RSIZE 3125     // NN / NR
#define NC    16       // edge chunks; partial = NC * 400 KB = 6.4 MB
#define PER   (NE / 4 / NC)   // 25000 int4s per chunk

// ======================= LDS-privatized edge passes =======================

__global__ __launch_bounds__(1024) void k_cnt32(const int4* __restrict__ dst4, int* __restrict__ partial) {
    __shared__ int tab[RSIZE];
    const int c = blockIdx.x, r = blockIdx.y;
    for (int j = threadIdx.x; j < RSIZE; j += 1024) tab[j] = 0;
    __syncthreads();
    const int base = r * RSIZE;
    const int i0 = c * PER;
    for (int i = i0 + (int)threadIdx.x; i < i0 + PER; i += 1024) {
        int4 d = dst4[i];
        unsigned a;
        a = (unsigned)(d.x - base); if (a < RSIZE) atomicAdd(&tab[a], 1);
        a = (unsigned)(d.y - base); if (a < RSIZE) atomicAdd(&tab[a], 1);
        a = (unsigned)(d.z - base); if (a < RSIZE) atomicAdd(&tab[a], 1);
        a = (unsigned)(d.w - base); if (a < RSIZE) atomicAdd(&tab[a], 1);
    }
    __syncthreads();
    int* out = partial + (size_t)(r * NC + c) * RSIZE;
    for (int j = threadIdx.x; j < RSIZE; j += 1024) out[j] = tab[j];
}

// scatter val[dst] keyed by src (used for ws pass with val=invc, t pass with val=u)
__global__ __launch_bounds__(1024) void k_scat32(const int4* __restrict__ src4, const int4* __restrict__ dst4,
                                                 const float* __restrict__ val, float* __restrict__ partial) {
    __shared__ float tab[RSIZE];
    const int c = blockIdx.x, r = blockIdx.y;
    for (int j = threadIdx.x; j < RSIZE; j += 1024) tab[j] = 0.f;
    __syncthreads();
    const int base = r * RSIZE;
    const int i0 = c * PER;
    for (int i = i0 + (int)threadIdx.x; i < i0 + PER; i += 1024) {
        int4 s = src4[i];
        int4 d = dst4[i];
        unsigned a;
        a = (unsigned)(s.x - base); if (a < RSIZE) atomicAdd(&tab[a], val[d.x]);
        a = (unsigned)(s.y - base); if (a < RSIZE) atomicAdd(&tab[a], val[d.y]);
        a = (unsigned)(s.z - base); if (a < RSIZE) atomicAdd(&tab[a], val[d.z]);
        a = (unsigned)(s.w - base); if (a < RSIZE) atomicAdd(&tab[a], val[d.w]);
    }
    __syncthreads();
    float* out = partial + (size_t)(r * NC + c) * RSIZE;
    for (int j = threadIdx.x; j < RSIZE; j += 1024) out[j] = tab[j];
}

__global__ __launch_bounds__(256) void k_merge_invc(const int* __restrict__ partial, float* __restrict__ invc) {
    int i = blockIdx.x * 256 + threadIdx.x;
    if (i >= NN) return;
    int r = i / RSIZE, j = i - r * RSIZE;
    const int* p = partial + (size_t)r * NC * RSIZE + j;
    int cn = 0;
    #pragma unroll
    for (int c = 0; c < NC; ++c) cn += p[(size_t)c * RSIZE];
    invc[i] = 1.0f / (float)(cn > 0 ? cn : 1);
}

__global__ __launch_bounds__(256) void k_merge_ws(const float* __restrict__ partial, const float* __restrict__ invc,
                                                  float* __restrict__ ws, float* __restrict__ u) {
    int i = blockIdx.x * 256 + threadIdx.x;
    if (i >= NN) return;
    int r = i / RSIZE, j = i - r * RSIZE;
    const float* p = partial + (size_t)r * NC * RSIZE + j;
    float w = 0.f;
    #pragma unroll
    for (int c = 0; c < NC; ++c) w += p[(size_t)c * RSIZE];
    ws[i] = w;
    u[i] = w * invc[i];
}

__global__ __launch_bounds__(256) void k_merge_t(const float* __restrict__ partial, float* __restrict__ t) {
    int i = blockIdx.x * 256 + threadIdx.x;
    if (i >= NN) return;
    int r = i / RSIZE, j = i - r * RSIZE;
    const float* p = partial + (size_t)r * NC * RSIZE + j;
    float v = 0.f;
    #pragma unroll
    for (int c = 0; c < NC; ++c) v += p[(size_t)c * RSIZE];
    t[i] = v;
}

// ======================= device-scope fallback (tiny ws_size) =======================

__global__ __launch_bounds__(256) void k_count_dev(const int4* __restrict__ dst4, int* __restrict__ cnt) {
    int i = blockIdx.x * 256 + threadIdx.x;
    if (i >= NE / 4) return;
    int4 d = dst4[i];
    atomicAdd(&cnt[d.x], 1); atomicAdd(&cnt[d.y], 1);
    atomicAdd(&cnt[d.z], 1); atomicAdd(&cnt[d.w], 1);
}

__global__ __launch_bounds__(256) void k_inv_dev(const int* __restrict__ cnt, float* __restrict__ invc) {
    int i = blockIdx.x * 256 + threadIdx.x;
    if (i >= NN) return;
    int c = cnt[i];
    invc[i] = 1.0f / (float)(c > 0 ? c : 1);
}

__global__ __launch_bounds__(256) void k_ws_dev(const int4* __restrict__ src4, const int4* __restrict__ dst4,
                                                const float* __restrict__ invc, float* __restrict__ ws) {
    int i = blockIdx.x * 256 + threadIdx.x;
    if (i >= NE / 4) return;
    int4 s = src4[i];
    int4 d = dst4[i];
    atomicAdd(&ws[s.x], invc[d.x]); atomicAdd(&ws[s.y], invc[d.y]);
    atomicAdd(&ws[s.z], invc[d.z]); atomicAdd(&ws[s.w], invc[d.w]);
}

__global__ __launch_bounds__(256) void k_u_dev(const float* __restrict__ ws, const float* __restrict__ invc,
                                               float* __restrict__ u) {
    int i = blockIdx.x * 256 + threadIdx.x;
    if (i >= NN) return;
    u[i] = ws[i] * invc[i];
}

__global__ __launch_bounds__(256) void k_t_dev(const int4* __restrict__ src4, const int4* __restrict__ dst4,
                                               const float* __restrict__ u, float* __restrict__ t) {
    int i = blockIdx.x * 256 + threadIdx.x;
    if (i >= NE / 4) return;
    int4 s = src4[i];
    int4 d = dst4[i];
    atomicAdd(&t[s.x], u[d.x]); atomicAdd(&t[s.y], u[d.y]);
    atomicAdd(&t[s.z], u[d.z]); atomicAdd(&t[s.w], u[d.w]);
}

// ======================= shared tail =======================

// Three weighted feature sums over x [NN,128]; grid 2048 for latency hiding.
__global__ __launch_bounds__(256) void k_featsums2k(const float* __restrict__ x,
                                                    const float* __restrict__ ws,
                                                    const float* __restrict__ t,
                                                    float* __restrict__ sums) {
    int lane = threadIdx.x & 31;
    int grp  = threadIdx.x >> 5;          // 0..7
    int row0 = blockIdx.x * 8 + grp;
    int rstride = gridDim.x * 8;

    float sx0=0,sx1=0,sx2=0,sx3=0;
    float sw0=0,sw1=0,sw2=0,sw3=0;
    float st0=0,st1=0,st2=0,st3=0;
    float wsum = 0.f;

    for (int r = row0; r < NN; r += rstride) {
        const float4* xr = (const float4*)(x + (size_t)r * FEAT);
        float4 v = xr[lane];
        float wr = ws[r];
        float tr = t[r];
        sx0 += v.x; sx1 += v.y; sx2 += v.z; sx3 += v.w;
        sw0 += wr*v.x; sw1 += wr*v.y; sw2 += wr*v.z; sw3 += wr*v.w;
        st0 += tr*v.x; st1 += tr*v.y; st2 += tr*v.z; st3 += tr*v.w;
        if (lane == 0) wsum += wr;
    }

    __shared__ float shx[8][32][4];
    __shared__ float shw[8][32][4];
    __shared__ float sht[8][32][4];
    __shared__ float shwsum[8];
    shx[grp][lane][0]=sx0; shx[grp][lane][1]=sx1; shx[grp][lane][2]=sx2; shx[grp][lane][3]=sx3;
    shw[grp][lane][0]=sw0; shw[grp][lane][1]=sw1; shw[grp][lane][2]=sw2; shw[grp][lane][3]=sw3;
    sht[grp][lane][0]=st0; sht[grp][lane][1]=st1; sht[grp][lane][2]=st2; sht[grp][lane][3]=st3;
    if (lane == 0) shwsum[grp] = wsum;
    __syncthreads();

    if (grp == 0) {
        float ax[4], aw[4], at[4];
        #pragma unroll
        for (int c = 0; c < 4; ++c) { ax[c]=shx[0][lane][c]; aw[c]=shw[0][lane][c]; at[c]=sht[0][lane][c]; }
        #pragma unroll
        for (int g = 1; g < 8; ++g) {
            #pragma unroll
            for (int c = 0; c < 4; ++c) {
                ax[c]+=shx[g][lane][c]; aw[c]+=shw[g][lane][c]; at[c]+=sht[g][lane][c];
            }
        }
        #pragma unroll
        for (int c = 0; c < 4; ++c) {
            atomicAdd(&sums[        4*lane + c], ax[c]);
            atomicAdd(&sums[FEAT  + 4*lane + c], aw[c]);
            atomicAdd(&sums[2*FEAT+ 4*lane + c], at[c]);
        }
        if (lane == 0) {
            float w = shwsum[0];
            #pragma unroll
            for (int g = 1; g < 8; ++g) w += shwsum[g];
            atomicAdd(&sums[3*FEAT], w);
        }
    }
}

__global__ __launch_bounds__(128) void k_final(const float* __restrict__ sums,
                                               const float* __restrict__ W1l, const float* __restrict__ W1r,
                                               const float* __restrict__ b1,
                                               const float* __restrict__ W2l, const float* __restrict__ W2r,
                                               const float* __restrict__ b2,
                                               const float* __restrict__ Wout, const float* __restrict__ bout,
                                               float* __restrict__ out) {
    __shared__ float Sx[FEAT], Sw[FEAT], St[FEAT], M1[FEAT], S2[FEAT], G[FEAT];
    __shared__ float Wsum;
    int f = threadIdx.x;
    Sx[f] = sums[f];
    Sw[f] = sums[FEAT + f];
    St[f] = sums[2*FEAT + f];
    if (f == 0) Wsum = sums[3*FEAT];
    __syncthreads();

    float m1 = (float)NN * b1[f];
    float s2 = Wsum * b1[f];
    for (int k = 0; k < FEAT; ++k) {
        float wl = W1l[k*FEAT + f];
        float wr = W1r[k*FEAT + f];
        m1 += Sw[k]*wl + Sx[k]*wr;
        s2 += St[k]*wl + Sw[k]*wr;
    }
    M1[f] = m1; S2[f] = s2;
    __syncthreads();

    float g = 0.f;
    for (int k = 0; k < FEAT; ++k)
        g += S2[k]*W2l[k*FEAT + f] + M1[k]*W2r[k*FEAT + f];
    g = g * (1.0f/(float)NN) + b2[f];
    G[f] = g;
    __syncthreads();

    if (f < NCLS) {
        float o = bout[f];
        for (int k = 0; k < FEAT; ++k)
            o += G[k]*Wout[k*NCLS + f];
        out[f] = o;
    }
}

// ======================= driver =======================

extern "C" void kernel_launch(void* const* d_in, const int* in_sizes, int n_in,
                              void* d_out, int out_size, void* d_ws, size_t ws_size,
                              hipStream_t stream) {
    const float* x    = (const float*)d_in[0];
    const int*   ei   = (const int*)d_in[1];     // [2, NE] flat: src then dst (int32 on device)
    const float* W1l  = (const float*)d_in[2];
    const float* W1r  = (const float*)d_in[3];
    const float* b1   = (const float*)d_in[4];
    const float* W2l  = (const float*)d_in[5];
    const float* W2r  = (const float*)d_in[6];
    const float* b2   = (const float*)d_in[7];
    const float* Wout = (const float*)d_in[8];
    const float* bout = (const float*)d_in[9];
    float* out = (float*)d_out;

    const int4* src4 = (const int4*)ei;
    const int4* dst4 = (const int4*)(ei + NE);

    const size_t need_lds = ((size_t)NR * NC * RSIZE + 640 + (size_t)4 * NN) * 4;  // ~8.0 MB

    if (ws_size >= need_lds) {
        // layout: partial[NR*NC*RSIZE] | sums[640] | invc[NN] | ws[NN] | u[NN] | t[NN]
        float* partial = (float*)d_ws;
        size_t po = (size_t)NR * NC * RSIZE;
        float* sums = (float*)d_ws + po;
        float* invc = (float*)d_ws + po + 640;
        float* ws   = (float*)d_ws + po + 640 + (size_t)NN;
        float* u    = (float*)d_ws + po + 640 + (size_t)2*NN;
        float* t    = (float*)d_ws + po + 640 + (size_t)3*NN;

        hipMemsetAsync(sums, 0, 640 * 4, stream);   // partial fully written, no init

        dim3 eg(NC, NR);                            // 512 blocks = 2/CU over 256 CUs
        const int NB = (NN + 255) / 256;

        k_cnt32<<<eg, 1024, 0, stream>>>(dst4, (int*)partial);
        k_merge_invc<<<NB, 256, 0, stream>>>((const int*)partial, invc);
        k_scat32<<<eg, 1024, 0, stream>>>(src4, dst4, invc, partial);
        k_merge_ws<<<NB, 256, 0, stream>>>(partial, invc, ws, u);
        k_scat32<<<eg, 1024, 0, stream>>>(src4, dst4, u, partial);
        k_merge_t<<<NB, 256, 0, stream>>>(partial, t);
        k_featsums2k<<<2048, 256, 0, stream>>>(x, ws, t, sums);
        k_final<<<1, 128, 0, stream>>>(sums, W1l, W1r, b1, W2l, W2r, b2, Wout, bout, out);
    } else {
        // device-scope atomic fallback (~2.1 MB ws)
        int*   cnt  = (int*)d_ws;
        float* wsv  = (float*)d_ws + NN;
        float* t    = (float*)d_ws + 2*NN;
        float* sums = (float*)d_ws + 3*NN;
        float* invc = (float*)d_ws + 3*NN + 640;
        float* u    = (float*)d_ws + 3*NN + 640 + NN;

        hipMemsetAsync(d_ws, 0, ((size_t)3*NN + 640) * 4, stream);

        const int EB4 = (NE/4 + 255) / 256;
        const int NB  = (NN + 255) / 256;
        k_count_dev<<<EB4, 256, 0, stream>>>(dst4, cnt);
        k_inv_dev<<<NB, 256, 0, stream>>>(cnt, invc);
        k_ws_dev<<<EB4, 256, 0, stream>>>(src4, dst4, invc, wsv);
        k_u_dev<<<NB, 256, 0, stream>>>(wsv, invc, u);
        k_t_dev<<<EB4, 256, 0, stream>>>(src4, dst4, u, t);
        k_featsums2k<<<2048, 256, 0, stream>>>(x, wsv, t, sums);
        k_final<<<1, 128, 0, stream>>>(sums, W1l, W1r, b1, W2l, W2r, b2, Wout, bout, out);
    }
}

// Round 6
// 205.668 us; speedup vs baseline: 1.9459x; 1.9459x over previous
//
#include <hip/hip_runtime.h>

// GraphSAGE (2x SAGEConv mean + global_mean_pool + linear) collapsed algebraically:
// out = (((St@W1l + Sw@W1r + Wsum*b1) @ W2l + (Sw@W1l + Sx@W1r + N*b1) @ W2r)/N + b2) @ Wout + bout
// invc_i = 1/max(indeg_i,1), ws_j = sum_{e:src=j} invc[dst_e], u_j = ws_j*invc_j,
// t_k = sum_{e:src=k} u[dst_e]; Sx/Sw/St = weighted column sums of x; Wsum = sum ws.
//
// R5: (1) featsums epilogue atomics (262k device atomics on 385 words, the
// 208 us R4 disaster) replaced by two-stage dense reduction: stage-1 blocks
// write partials to [385][2048] scratch (aliases `partial`), stage-2 does
// coalesced row sums. (2) Edge passes NR=16/NC=16: 256 blocks = 1/CU on all
// 256 CUs, 16x scan redundancy (R4's NR=32 was HBM-bound on 32x redundancy).

#define NN    100000
#define NE    1600000
#define FEAT  128
#define NCLS  40
#define NR    16
#define RSIZE 6250     // NN / NR
#define NC    16       // edge chunks; partial = NR*NC*RSIZE*4 = 6.4 MB
#define PER   (NE / 4 / NC)   // 25000 int4s per chunk
#define FSB   2048     // featsums stage-1 blocks

// ======================= LDS-privatized edge passes =======================

__global__ __launch_bounds__(1024) void k_cnt16(const int4* __restrict__ dst4, int* __restrict__ partial) {
    __shared__ int tab[RSIZE];
    const int c = blockIdx.x, r = blockIdx.y;
    for (int j = threadIdx.x; j < RSIZE; j += 1024) tab[j] = 0;
    __syncthreads();
    const int base = r * RSIZE;
    const int i0 = c * PER;
    for (int i = i0 + (int)threadIdx.x; i < i0 + PER; i += 1024) {
        int4 d = dst4[i];
        unsigned a;
        a = (unsigned)(d.x - base); if (a < RSIZE) atomicAdd(&tab[a], 1);
        a = (unsigned)(d.y - base); if (a < RSIZE) atomicAdd(&tab[a], 1);
        a = (unsigned)(d.z - base); if (a < RSIZE) atomicAdd(&tab[a], 1);
        a = (unsigned)(d.w - base); if (a < RSIZE) atomicAdd(&tab[a], 1);
    }
    __syncthreads();
    int* out = partial + (size_t)(r * NC + c) * RSIZE;
    for (int j = threadIdx.x; j < RSIZE; j += 1024) out[j] = tab[j];
}

// scatter val[dst] keyed by src (ws pass: val=invc; t pass: val=u)
__global__ __launch_bounds__(1024) void k_scat16(const int4* __restrict__ src4, const int4* __restrict__ dst4,
                                                 const float* __restrict__ val, float* __restrict__ partial) {
    __shared__ float tab[RSIZE];
    const int c = blockIdx.x, r = blockIdx.y;
    for (int j = threadIdx.x; j < RSIZE; j += 1024) tab[j] = 0.f;
    __syncthreads();
    const int base = r * RSIZE;
    const int i0 = c * PER;
    for (int i = i0 + (int)threadIdx.x; i < i0 + PER; i += 1024) {
        int4 s = src4[i];
        int4 d = dst4[i];
        unsigned a;
        a = (unsigned)(s.x - base); if (a < RSIZE) atomicAdd(&tab[a], val[d.x]);
        a = (unsigned)(s.y - base); if (a < RSIZE) atomicAdd(&tab[a], val[d.y]);
        a = (unsigned)(s.z - base); if (a < RSIZE) atomicAdd(&tab[a], val[d.z]);
        a = (unsigned)(s.w - base); if (a < RSIZE) atomicAdd(&tab[a], val[d.w]);
    }
    __syncthreads();
    float* out = partial + (size_t)(r * NC + c) * RSIZE;
    for (int j = threadIdx.x; j < RSIZE; j += 1024) out[j] = tab[j];
}

__global__ __launch_bounds__(256) void k_merge_invc(const int* __restrict__ partial, float* __restrict__ invc) {
    int i = blockIdx.x * 256 + threadIdx.x;
    if (i >= NN) return;
    int r = i / RSIZE, j = i - r * RSIZE;
    const int* p = partial + (size_t)r * NC * RSIZE + j;
    int cn = 0;
    #pragma unroll
    for (int c = 0; c < NC; ++c) cn += p[(size_t)c * RSIZE];
    invc[i] = 1.0f / (float)(cn > 0 ? cn : 1);
}

__global__ __launch_bounds__(256) void k_merge_ws(const float* __restrict__ partial, const float* __restrict__ invc,
                                                  float* __restrict__ ws, float* __restrict__ u) {
    int i = blockIdx.x * 256 + threadIdx.x;
    if (i >= NN) return;
    int r = i / RSIZE, j = i - r * RSIZE;
    const float* p = partial + (size_t)r * NC * RSIZE + j;
    float w = 0.f;
    #pragma unroll
    for (int c = 0; c < NC; ++c) w += p[(size_t)c * RSIZE];
    ws[i] = w;
    u[i] = w * invc[i];
}

__global__ __launch_bounds__(256) void k_merge_t(const float* __restrict__ partial, float* __restrict__ t) {
    int i = blockIdx.x * 256 + threadIdx.x;
    if (i >= NN) return;
    int r = i / RSIZE, j = i - r * RSIZE;
    const float* p = partial + (size_t)r * NC * RSIZE + j;
    float v = 0.f;
    #pragma unroll
    for (int c = 0; c < NC; ++c) v += p[(size_t)c * RSIZE];
    t[i] = v;
}

// ======================= featsums: two-stage, no atomics =======================

// Stage 1: grid FSB x 256 thr; block writes 385 partials to p1[idx*FSB + blk].
__global__ __launch_bounds__(256) void k_fs1(const float* __restrict__ x,
                                             const float* __restrict__ ws,
                                             const float* __restrict__ t,
                                             float* __restrict__ p1) {
    int lane = threadIdx.x & 31;
    int grp  = threadIdx.x >> 5;          // 0..7
    int row0 = blockIdx.x * 8 + grp;
    const int rstride = FSB * 8;

    float sx0=0,sx1=0,sx2=0,sx3=0;
    float sw0=0,sw1=0,sw2=0,sw3=0;
    float st0=0,st1=0,st2=0,st3=0;
    float wsum = 0.f;

    for (int r = row0; r < NN; r += rstride) {
        const float4* xr = (const float4*)(x + (size_t)r * FEAT);
        float4 v = xr[lane];
        float wr = ws[r];
        float tr = t[r];
        sx0 += v.x; sx1 += v.y; sx2 += v.z; sx3 += v.w;
        sw0 += wr*v.x; sw1 += wr*v.y; sw2 += wr*v.z; sw3 += wr*v.w;
        st0 += tr*v.x; st1 += tr*v.y; st2 += tr*v.z; st3 += tr*v.w;
        if (lane == 0) wsum += wr;
    }

    __shared__ float shx[8][32][4];
    __shared__ float shw[8][32][4];
    __shared__ float sht[8][32][4];
    __shared__ float shwsum[8];
    shx[grp][lane][0]=sx0; shx[grp][lane][1]=sx1; shx[grp][lane][2]=sx2; shx[grp][lane][3]=sx3;
    shw[grp][lane][0]=sw0; shw[grp][lane][1]=sw1; shw[grp][lane][2]=sw2; shw[grp][lane][3]=sw3;
    sht[grp][lane][0]=st0; sht[grp][lane][1]=st1; sht[grp][lane][2]=st2; sht[grp][lane][3]=st3;
    if (lane == 0) shwsum[grp] = wsum;
    __syncthreads();

    if (grp == 0) {
        const int b = blockIdx.x;
        float ax[4], aw[4], at[4];
        #pragma unroll
        for (int c = 0; c < 4; ++c) { ax[c]=shx[0][lane][c]; aw[c]=shw[0][lane][c]; at[c]=sht[0][lane][c]; }
        #pragma unroll
        for (int g = 1; g < 8; ++g) {
            #pragma unroll
            for (int c = 0; c < 4; ++c) {
                ax[c]+=shx[g][lane][c]; aw[c]+=shw[g][lane][c]; at[c]+=sht[g][lane][c];
            }
        }
        #pragma unroll
        for (int c = 0; c < 4; ++c) {
            p1[(size_t)(        4*lane + c) * FSB + b] = ax[c];
            p1[(size_t)(FEAT  + 4*lane + c) * FSB + b] = aw[c];
            p1[(size_t)(2*FEAT+ 4*lane + c) * FSB + b] = at[c];
        }
        if (lane == 0) {
            float w = shwsum[0];
            #pragma unroll
            for (int g = 1; g < 8; ++g) w += shwsum[g];
            p1[(size_t)(3*FEAT) * FSB + b] = w;
        }
    }
}

// Stage 2: grid 385 blocks x 256 thr; coalesced row sum -> sums[v].
__global__ __launch_bounds__(256) void k_fs2(const float* __restrict__ p1, float* __restrict__ sums) {
    const int v = blockIdx.x;
    float s = 0.f;
    for (int b = threadIdx.x; b < FSB; b += 256) s += p1[(size_t)v * FSB + b];
    __shared__ float sh[256];
    sh[threadIdx.x] = s;
    __syncthreads();
    for (int off = 128; off > 0; off >>= 1) {
        if (threadIdx.x < off) sh[threadIdx.x] += sh[threadIdx.x + off];
        __syncthreads();
    }
    if (threadIdx.x == 0) sums[v] = sh[0];
}

// ======================= device-scope fallback (tiny ws_size) =======================

__global__ __launch_bounds__(256) void k_count_dev(const int4* __restrict__ dst4, int* __restrict__ cnt) {
    int i = blockIdx.x * 256 + threadIdx.x;
    if (i >= NE / 4) return;
    int4 d = dst4[i];
    atomicAdd(&cnt[d.x], 1); atomicAdd(&cnt[d.y], 1);
    atomicAdd(&cnt[d.z], 1); atomicAdd(&cnt[d.w], 1);
}

__global__ __launch_bounds__(256) void k_inv_dev(const int* __restrict__ cnt, float* __restrict__ invc) {
    int i = blockIdx.x * 256 + threadIdx.x;
    if (i >= NN) return;
    int c = cnt[i];
    invc[i] = 1.0f / (float)(c > 0 ? c : 1);
}

__global__ __launch_bounds__(256) void k_ws_dev(const int4* __restrict__ src4, const int4* __restrict__ dst4,
                                                const float* __restrict__ invc, float* __restrict__ ws) {
    int i = blockIdx.x * 256 + threadIdx.x;
    if (i >= NE / 4) return;
    int4 s = src4[i];
    int4 d = dst4[i];
    atomicAdd(&ws[s.x], invc[d.x]); atomicAdd(&ws[s.y], invc[d.y]);
    atomicAdd(&ws[s.z], invc[d.z]); atomicAdd(&ws[s.w], invc[d.w]);
}

__global__ __launch_bounds__(256) void k_u_dev(const float* __restrict__ ws, const float* __restrict__ invc,
                                               float* __restrict__ u) {
    int i = blockIdx.x * 256 + threadIdx.x;
    if (i >= NN) return;
    u[i] = ws[i] * invc[i];
}

__global__ __launch_bounds__(256) void k_t_dev(const int4* __restrict__ src4, const int4* __restrict__ dst4,
                                               const float* __restrict__ u, float* __restrict__ t) {
    int i = blockIdx.x * 256 + threadIdx.x;
    if (i >= NE / 4) return;
    int4 s = src4[i];
    int4 d = dst4[i];
    atomicAdd(&t[s.x], u[d.x]); atomicAdd(&t[s.y], u[d.y]);
    atomicAdd(&t[s.z], u[d.z]); atomicAdd(&t[s.w], u[d.w]);
}

// fallback featsums (grid 256, atomic epilogue — R3 behavior)
__global__ __launch_bounds__(256) void k_fs_atom(const float* __restrict__ x,
                                                 const float* __restrict__ ws,
                                                 const float* __restrict__ t,
                                                 float* __restrict__ sums) {
    int lane = threadIdx.x & 31;
    int grp  = threadIdx.x >> 5;
    int row0 = blockIdx.x * 8 + grp;
    int rstride = gridDim.x * 8;
    float sx0=0,sx1=0,sx2=0,sx3=0, sw0=0,sw1=0,sw2=0,sw3=0, st0=0,st1=0,st2=0,st3=0, wsum=0.f;
    for (int r = row0; r < NN; r += rstride) {
        const float4* xr = (const float4*)(x + (size_t)r * FEAT);
        float4 v = xr[lane];
        float wr = ws[r], tr = t[r];
        sx0+=v.x; sx1+=v.y; sx2+=v.z; sx3+=v.w;
        sw0+=wr*v.x; sw1+=wr*v.y; sw2+=wr*v.z; sw3+=wr*v.w;
        st0+=tr*v.x; st1+=tr*v.y; st2+=tr*v.z; st3+=tr*v.w;
        if (lane==0) wsum += wr;
    }
    __shared__ float shx[8][32][4], shw[8][32][4], sht[8][32][4], shwsum[8];
    shx[grp][lane][0]=sx0; shx[grp][lane][1]=sx1; shx[grp][lane][2]=sx2; shx[grp][lane][3]=sx3;
    shw[grp][lane][0]=sw0; shw[grp][lane][1]=sw1; shw[grp][lane][2]=sw2; shw[grp][lane][3]=sw3;
    sht[grp][lane][0]=st0; sht[grp][lane][1]=st1; sht[grp][lane][2]=st2; sht[grp][lane][3]=st3;
    if (lane==0) shwsum[grp]=wsum;
    __syncthreads();
    if (grp==0) {
        float ax[4], aw[4], at[4];
        #pragma unroll
        for (int c=0;c<4;++c){ax[c]=shx[0][lane][c];aw[c]=shw[0][lane][c];at[c]=sht[0][lane][c];}
        #pragma unroll
        for (int g=1;g<8;++g)
            #pragma unroll
            for (int c=0;c<4;++c){ax[c]+=shx[g][lane][c];aw[c]+=shw[g][lane][c];at[c]+=sht[g][lane][c];}
        #pragma unroll
        for (int c=0;c<4;++c){
            atomicAdd(&sums[        4*lane+c], ax[c]);
            atomicAdd(&sums[FEAT  + 4*lane+c], aw[c]);
            atomicAdd(&sums[2*FEAT+ 4*lane+c], at[c]);
        }
        if (lane==0){
            float w=shwsum[0];
            #pragma unroll
            for (int g=1;g<8;++g) w+=shwsum[g];
            atomicAdd(&sums[3*FEAT], w);
        }
    }
}

// ======================= shared epilogue =======================

__global__ __launch_bounds__(128) void k_final(const float* __restrict__ sums,
                                               const float* __restrict__ W1l, const float* __restrict__ W1r,
                                               const float* __restrict__ b1,
                                               const float* __restrict__ W2l, const float* __restrict__ W2r,
                                               const float* __restrict__ b2,
                                               const float* __restrict__ Wout, const float* __restrict__ bout,
                                               float* __restrict__ out) {
    __shared__ float Sx[FEAT], Sw[FEAT], St[FEAT], M1[FEAT], S2[FEAT], G[FEAT];
    __shared__ float Wsum;
    int f = threadIdx.x;
    Sx[f] = sums[f];
    Sw[f] = sums[FEAT + f];
    St[f] = sums[2*FEAT + f];
    if (f == 0) Wsum = sums[3*FEAT];
    __syncthreads();

    float m1 = (float)NN * b1[f];
    float s2 = Wsum * b1[f];
    for (int k = 0; k < FEAT; ++k) {
        float wl = W1l[k*FEAT + f];
        float wr = W1r[k*FEAT + f];
        m1 += Sw[k]*wl + Sx[k]*wr;
        s2 += St[k]*wl + Sw[k]*wr;
    }
    M1[f] = m1; S2[f] = s2;
    __syncthreads();

    float g = 0.f;
    for (int k = 0; k < FEAT; ++k)
        g += S2[k]*W2l[k*FEAT + f] + M1[k]*W2r[k*FEAT + f];
    g = g * (1.0f/(float)NN) + b2[f];
    G[f] = g;
    __syncthreads();

    if (f < NCLS) {
        float o = bout[f];
        for (int k = 0; k < FEAT; ++k)
            o += G[k]*Wout[k*NCLS + f];
        out[f] = o;
    }
}

// ======================= driver =======================

extern "C" void kernel_launch(void* const* d_in, const int* in_sizes, int n_in,
                              void* d_out, int out_size, void* d_ws, size_t ws_size,
                              hipStream_t stream) {
    const float* x    = (const float*)d_in[0];
    const int*   ei   = (const int*)d_in[1];     // [2, NE] flat: src then dst (int32 on device)
    const float* W1l  = (const float*)d_in[2];
    const float* W1r  = (const float*)d_in[3];
    const float* b1   = (const float*)d_in[4];
    const float* W2l  = (const float*)d_in[5];
    const float* W2r  = (const float*)d_in[6];
    const float* b2   = (const float*)d_in[7];
    const float* Wout = (const float*)d_in[8];
    const float* bout = (const float*)d_in[9];
    float* out = (float*)d_out;

    const int4* src4 = (const int4*)ei;
    const int4* dst4 = (const int4*)(ei + NE);

    const size_t need_lds = ((size_t)NR * NC * RSIZE + 640 + (size_t)4 * NN) * 4;  // ~8.0 MB

    if (ws_size >= need_lds) {
        // layout: partial[NR*NC*RSIZE] | sums[640] | invc[NN] | ws[NN] | u[NN] | t[NN]
        float* partial = (float*)d_ws;
        size_t po = (size_t)NR * NC * RSIZE;
        float* sums = (float*)d_ws + po;
        float* invc = (float*)d_ws + po + 640;
        float* ws   = (float*)d_ws + po + 640 + (size_t)NN;
        float* u    = (float*)d_ws + po + 640 + (size_t)2*NN;
        float* t    = (float*)d_ws + po + 640 + (size_t)3*NN;
        float* p1   = partial;   // featsums stage-1 scratch aliases partial (free after k_merge_t)

        dim3 eg(NC, NR);         // 256 blocks = 1/CU over 256 CUs
        const int NB = (NN + 255) / 256;

        k_cnt16<<<eg, 1024, 0, stream>>>(dst4, (int*)partial);
        k_merge_invc<<<NB, 256, 0, stream>>>((const int*)partial, invc);
        k_scat16<<<eg, 1024, 0, stream>>>(src4, dst4, invc, partial);
        k_merge_ws<<<NB, 256, 0, stream>>>(partial, invc, ws, u);
        k_scat16<<<eg, 1024, 0, stream>>>(src4, dst4, u, partial);
        k_merge_t<<<NB, 256, 0, stream>>>(partial, t);
        k_fs1<<<FSB, 256, 0, stream>>>(x, ws, t, p1);
        k_fs2<<<385, 256, 0, stream>>>(p1, sums);
        k_final<<<1, 128, 0, stream>>>(sums, W1l, W1r, b1, W2l, W2r, b2, Wout, bout, out);
    } else {
        // device-scope atomic fallback (~2.1 MB ws)
        int*   cnt  = (int*)d_ws;
        float* wsv  = (float*)d_ws + NN;
        float* t    = (float*)d_ws + 2*NN;
        float* sums = (float*)d_ws + 3*NN;
        float* invc = (float*)d_ws + 3*NN + 640;
        float* u    = (float*)d_ws + 3*NN + 640 + NN;

        hipMemsetAsync(d_ws, 0, ((size_t)3*NN + 640) * 4, stream);

        const int EB4 = (NE/4 + 255) / 256;
        const int NB  = (NN + 255) / 256;
        k_count_dev<<<EB4, 256, 0, stream>>>(dst4, cnt);
        k_inv_dev<<<NB, 256, 0, stream>>>(cnt, invc);
        k_ws_dev<<<EB4, 256, 0, stream>>>(src4, dst4, invc, wsv);
        k_u_dev<<<NB, 256, 0, stream>>>(wsv, invc, u);
        k_t_dev<<<EB4, 256, 0, stream>>>(src4, dst4, u, t);
        k_fs_atom<<<256, 256, 0, stream>>>(x, wsv, t, sums);
        k_final<<<1, 128, 0, stream>>>(sums, W1l, W1r, b1, W2l, W2r, b2, Wout, bout, out);
    }
}